// Round 11
// baseline (131.495 us; speedup 1.0000x reference)
//
#include <hip/hip_runtime.h>
#include <cstddef>

#define NCAPS  10
#define BATCH  256
#define NROUTE 1152
#define CIN    8
#define COUT   16
#define T      1024          // 16 waves; LDS 73.7KB -> 2 blocks/CU co-resident
#define NB     2             // batch elements per block (W economy: 755MB total)
#define NWAVE  (T / 64)
#define NBLK   (NCAPS * (BATCH / NB))   // 1280 blocks = 5 rounds/CU
#define PLANE  (NROUTE * 8)             // u32 (bf16x2) per b-plane = 9216
#define XPLANE (NROUTE * CIN)           // floats per x b-plane = 9216

// bijective 16B-unit swizzle (validated rounds 5-10): conflict-minimal ds_read
__device__ __forceinline__ unsigned swzu(unsigned unit) { return unit ^ ((unit >> 3) & 3u); }

// pack two fp32 -> bf16x2 (RNE), low16 = a
__device__ __forceinline__ unsigned pack_bf16(float a, float b) {
    unsigned ua = __float_as_uint(a); ua += 0x7fffu + ((ua >> 16) & 1u);
    unsigned ub = __float_as_uint(b); ub += 0x7fffu + ((ub >> 16) & 1u);
    return (ua >> 16) | (ub & 0xffff0000u);
}
__device__ __forceinline__ float blo(unsigned u) { return __uint_as_float(u << 16); }
__device__ __forceinline__ float bhi(unsigned u) { return __uint_as_float(u & 0xffff0000u); }

__device__ __forceinline__ float wave_sum(float v) {
    v += __shfl_xor(v, 1);  v += __shfl_xor(v, 2);  v += __shfl_xor(v, 4);
    v += __shfl_xor(v, 8);  v += __shfl_xor(v, 16); v += __shfl_xor(v, 32);
    return v;
}

// Component-splitting butterfly: reduces s[0..15] over 64 lanes. EVERY lane L
// ends with the wave total of comp(L&15), comp(L)=((L&1)<<3)|((L&2)<<1)|((L&4)>>1)|((L&8)>>3)
// (involution). Validated rounds 1-10 for lanes<16; the final xor16/xor32 folds
// make all 64 lanes hold the full total.
__device__ __forceinline__ float wave_sum16(float* s, int lane) {
#pragma unroll
    for (int j = 0; j < 8; ++j) {
        float snd = (lane & 1) ? s[j] : s[j + 8];
        float r = __shfl_xor(snd, 1);
        s[j] = ((lane & 1) ? s[j + 8] : s[j]) + r;
    }
#pragma unroll
    for (int j = 0; j < 4; ++j) {
        float snd = (lane & 2) ? s[j] : s[j + 4];
        float r = __shfl_xor(snd, 2);
        s[j] = ((lane & 2) ? s[j + 4] : s[j]) + r;
    }
#pragma unroll
    for (int j = 0; j < 2; ++j) {
        float snd = (lane & 4) ? s[j] : s[j + 2];
        float r = __shfl_xor(snd, 4);
        s[j] = ((lane & 4) ? s[j + 2] : s[j]) + r;
    }
    {
        float snd = (lane & 8) ? s[0] : s[1];
        float r = __shfl_xor(snd, 8);
        s[0] = ((lane & 8) ? s[1] : s[0]) + r;
    }
    s[0] += __shfl_xor(s[0], 16);
    s[0] += __shfl_xor(s[0], 32);
    return s[0];
}

union U4 { uint4 v; unsigned u[4]; };
union U2 { uint2 v; unsigned u[2]; };

// Phase-A unit (unchanged from R10): route r=u>>2, out-quad j4=u&3.
__device__ __forceinline__ void phaseA_unit(int u, const float* __restrict__ Wc,
                                            const float* __restrict__ xb,
                                            unsigned* prLDS) {
    const int r  = u >> 2;
    const int j4 = u & 3;
    float xs[NB][CIN];
#pragma unroll
    for (int b = 0; b < NB; ++b) {
        const float4* xq = (const float4*)(xb + (size_t)b * XPLANE + r * CIN);
        float4 xa = xq[0], xv = xq[1];
        xs[b][0] = xa.x; xs[b][1] = xa.y; xs[b][2] = xa.z; xs[b][3] = xa.w;
        xs[b][4] = xv.x; xs[b][5] = xv.y; xs[b][6] = xv.z; xs[b][7] = xv.w;
    }
    float4 acc[NB];
#pragma unroll
    for (int b = 0; b < NB; ++b) acc[b] = make_float4(0.f, 0.f, 0.f, 0.f);
    const float* wq = Wc + (size_t)r * (CIN * COUT) + j4 * 4;
#pragma unroll
    for (int i = 0; i < CIN; ++i) {
        float4 w = *(const float4*)(wq + i * COUT);
#pragma unroll
        for (int b = 0; b < NB; ++b) {
            acc[b].x = fmaf(xs[b][i], w.x, acc[b].x);
            acc[b].y = fmaf(xs[b][i], w.y, acc[b].y);
            acc[b].z = fmaf(xs[b][i], w.z, acc[b].z);
            acc[b].w = fmaf(xs[b][i], w.w, acc[b].w);
        }
    }
    const unsigned base = swzu(2u * (unsigned)r + (unsigned)(j4 >> 1)) * 4u
                        + (unsigned)(j4 & 1) * 2u;
#pragma unroll
    for (int b = 0; b < NB; ++b) {
        U2 q;
        q.u[0] = pack_bf16(acc[b].x, acc[b].y);
        q.u[1] = pack_bf16(acc[b].z, acc[b].w);
        *(uint2*)&prLDS[b * PLANE + base] = q.v;
    }
}

// launch_bounds(1024, 8): DELIBERATE 64-VGPR cap so 2 blocks/CU co-reside
// (phase-B live set engineered ~55 regs; R1's spill lesson applied, not repeated).
__global__ __launch_bounds__(T, 8) void caps_routing(const float* __restrict__ x,
                                                     const float* __restrict__ W,
                                                     float* __restrict__ out) {
    __shared__ unsigned prLDS[NB * PLANE];          // 73728 B: priors bf16x2, swizzled

    const int tid  = threadIdx.x;
    const int lane = tid & 63;
    const int wv   = tid >> 6;

    // XCD-aware swizzle: contiguous widx per XCD -> <=2 capsules -> W L2-resident
    int g    = blockIdx.x;
    int widx = (g & 7) * (NBLK / 8) + (g >> 3);   // bijective, 1280 % 8 == 0
    int c    = widx >> 7;                          // / (BATCH/NB = 128)
    int b0   = (widx & 127) * NB;

    const float* Wc = W + (size_t)c * (NROUTE * CIN * COUT);
    const float* xb = x + (size_t)b0 * XPLANE;

    // ---------------- Phase A: all 16 waves, 4608 units ---------------------
#pragma unroll 1
    for (int pass = 0; pass < 4; ++pass) {
        phaseA_unit(pass * T + tid, Wc, xb, prLDS);
    }
    if (tid < 512) {
        phaseA_unit(4 * T + tid, Wc, xb, prLDS);
    }
    __syncthreads();   // the ONLY block barrier

    // ---------------- Phase B: ONE wave per batch element -------------------
    // 1152 = 64*18 exactly: 18 routes/lane, no leftover. No block barriers:
    // butterfly + squash + V-broadcast all wave-internal; V in registers.
    if (wv < NB) {
        const int b = wv;
        const unsigned pbase = (unsigned)b * PLANE;
        const int comp = ((lane & 1) << 3) | ((lane & 2) << 1) | ((lane & 4) >> 1) | ((lane & 8) >> 3);

        float V[COUT];     // cumulative output sum (linearity: logit = p . V)
#pragma unroll
        for (int j = 0; j < COUT; ++j) V[j] = 0.f;

#pragma unroll 1
        for (int it = 0; it < 3; ++it) {
            float s16[COUT];
#pragma unroll
            for (int o = 0; o < COUT; ++o) s16[o] = 0.f;
            float se = 0.f;

            // 18 routes r = k*64 + lane, 1-deep manual prefetch
            U4 qa, qb;
            {
                const unsigned u0 = 2u * (unsigned)lane;
                qa.v = *(const uint4*)&prLDS[pbase + swzu(u0) * 4u];
                qb.v = *(const uint4*)&prLDS[pbase + swzu(u0 + 1u) * 4u];
            }
#pragma unroll 1
            for (int k = 0; k < 18; ++k) {
                U4 na, nb;
                if (k < 17) {
                    const unsigned un = 2u * (unsigned)((k + 1) * 64 + lane);
                    na.v = *(const uint4*)&prLDS[pbase + swzu(un) * 4u];
                    nb.v = *(const uint4*)&prLDS[pbase + swzu(un + 1u) * 4u];
                }
                float e;
                if (it > 0) {
                    float d0 = 0.f, d1 = 0.f;   // two chains -> halved latency
#pragma unroll
                    for (int q = 0; q < 4; ++q) {
                        d0 = fmaf(blo(qa.u[q]), V[2 * q],     d0);
                        d1 = fmaf(bhi(qa.u[q]), V[2 * q + 1], d1);
                        d0 = fmaf(blo(qb.u[q]), V[8 + 2 * q], d0);
                        d1 = fmaf(bhi(qb.u[q]), V[9 + 2 * q], d1);
                    }
                    e = __expf(d0 + d1);   // logit bounded ~|45|, fp32 exp safe
                } else {
                    e = 1.f;               // iter 0: softmax of zeros
                }
                se += e;
#pragma unroll
                for (int q = 0; q < 4; ++q) {
                    s16[2 * q]     = fmaf(e, blo(qa.u[q]), s16[2 * q]);
                    s16[2 * q + 1] = fmaf(e, bhi(qa.u[q]), s16[2 * q + 1]);
                    s16[8 + 2 * q] = fmaf(e, blo(qb.u[q]), s16[8 + 2 * q]);
                    s16[9 + 2 * q] = fmaf(e, bhi(qb.u[q]), s16[9 + 2 * q]);
                }
                qa = na; qb = nb;
            }

            const float S  = wave_sum16(s16, lane);   // all lanes: comp(lane&15) total
            const float SE = wave_sum(se);
            const float tt = S / SE;
            float pq = tt * tt;
            pq += __shfl_xor(pq, 1); pq += __shfl_xor(pq, 2);
            pq += __shfl_xor(pq, 4); pq += __shfl_xor(pq, 8);   // |s|^2 over 16 comps
            const float scale = pq / ((1.f + pq) * sqrtf(pq));
            const float val = tt * scale;               // lane holds out[comp(lane&15)]

            if (it == 2) {
                if (lane < 16)
                    out[((size_t)c * BATCH + b0 + b) * COUT + comp] = val;
            } else {
                // V[j] lives in lane comp(j) (involution) -> 16 broadcasts
#pragma unroll
                for (int j = 0; j < COUT; ++j) {
                    const int src = ((j & 1) << 3) | ((j & 2) << 1) | ((j & 4) >> 1) | ((j & 8) >> 3);
                    V[j] += __shfl(val, src);
                }
            }
        }
    }
}

extern "C" void kernel_launch(void* const* d_in, const int* in_sizes, int n_in,
                              void* d_out, int out_size, void* d_ws, size_t ws_size,
                              hipStream_t stream) {
    const float* x = (const float*)d_in[0];
    const float* w = (const float*)d_in[1];
    float* out = (float*)d_out;
    hipLaunchKernelGGL(caps_routing, dim3(NBLK), dim3(T), 0, stream, x, w, out);
}

// Round 12
// 81.962 us; speedup vs baseline: 1.6043x; 1.6043x over previous
//
#include <hip/hip_runtime.h>
#include <cstddef>

#define NCAPS  10
#define BATCH  256
#define NROUTE 1152
#define CIN    8
#define COUT   16
#define T      1024          // 16 waves; LDS ~149KB -> 1 block/CU
#define NB     4             // batch elements per block: W L2 traffic = 378MB
#define NWAVE  (T / 64)
#define NBLK   (NCAPS * (BATCH / NB))   // 640 blocks = 2.5 rounds/CU
#define PLANE  (NROUTE * 8)             // u32 (bf16x2) per b-plane = 9216
#define XPLANE (NROUTE * CIN)           // floats per x b-plane = 9216

// bijective 16B-unit swizzle (validated rounds 5-11): conflict-minimal ds_read
__device__ __forceinline__ unsigned swzu(unsigned unit) { return unit ^ ((unit >> 3) & 3u); }

// pack two fp32 -> bf16x2 (RNE), low16 = a
__device__ __forceinline__ unsigned pack_bf16(float a, float b) {
    unsigned ua = __float_as_uint(a); ua += 0x7fffu + ((ua >> 16) & 1u);
    unsigned ub = __float_as_uint(b); ub += 0x7fffu + ((ub >> 16) & 1u);
    return (ua >> 16) | (ub & 0xffff0000u);
}
__device__ __forceinline__ float blo(unsigned u) { return __uint_as_float(u << 16); }
__device__ __forceinline__ float bhi(unsigned u) { return __uint_as_float(u & 0xffff0000u); }

__device__ __forceinline__ float wave_sum(float v) {
    v += __shfl_xor(v, 1);  v += __shfl_xor(v, 2);  v += __shfl_xor(v, 4);
    v += __shfl_xor(v, 8);  v += __shfl_xor(v, 16); v += __shfl_xor(v, 32);
    return v;
}

// Component-splitting butterfly: reduces s[0..15] over 64 lanes. Lane L (L<16)
// ends with the wave total of comp(L)=((L&1)<<3)|((L&2)<<1)|((L&4)>>1)|((L&8)>>3).
__device__ __forceinline__ float wave_sum16(float* s, int lane) {
#pragma unroll
    for (int j = 0; j < 8; ++j) {
        float snd = (lane & 1) ? s[j] : s[j + 8];
        float r = __shfl_xor(snd, 1);
        s[j] = ((lane & 1) ? s[j + 8] : s[j]) + r;
    }
#pragma unroll
    for (int j = 0; j < 4; ++j) {
        float snd = (lane & 2) ? s[j] : s[j + 4];
        float r = __shfl_xor(snd, 2);
        s[j] = ((lane & 2) ? s[j + 4] : s[j]) + r;
    }
#pragma unroll
    for (int j = 0; j < 2; ++j) {
        float snd = (lane & 4) ? s[j] : s[j + 2];
        float r = __shfl_xor(snd, 4);
        s[j] = ((lane & 4) ? s[j + 2] : s[j]) + r;
    }
    {
        float snd = (lane & 8) ? s[0] : s[1];
        float r = __shfl_xor(snd, 8);
        s[0] = ((lane & 8) ? s[1] : s[0]) + r;
    }
    s[0] += __shfl_xor(s[0], 16);
    s[0] += __shfl_xor(s[0], 32);
    return s[0];
}

union U4 { uint4 v; unsigned u[4]; };
union U2 { uint2 v; unsigned u[2]; };

// Phase-A unit (R6 verbatim — measured 52 VGPR, zero spill at NB=4):
// unit u -> route r=u>>3, out-pair j=u&7 (outs 2j, 2j+1). W float2, x broadcast.
__device__ __forceinline__ void phaseA_unit(int u, const float* __restrict__ Wc,
                                            const float* __restrict__ xb,
                                            unsigned* prLDS) {
    const int r = u >> 3;
    const int j = u & 7;
    float xs[NB][CIN];
#pragma unroll
    for (int b = 0; b < NB; ++b) {
        const float4* xq = (const float4*)(xb + (size_t)b * XPLANE + r * CIN);
        float4 xa = xq[0], xv = xq[1];      // 8-lane broadcast
        xs[b][0] = xa.x; xs[b][1] = xa.y; xs[b][2] = xa.z; xs[b][3] = xa.w;
        xs[b][4] = xv.x; xs[b][5] = xv.y; xs[b][6] = xv.z; xs[b][7] = xv.w;
    }
    float2 acc[NB];
#pragma unroll
    for (int b = 0; b < NB; ++b) { acc[b].x = 0.f; acc[b].y = 0.f; }
    const float* wq = Wc + (size_t)r * (CIN * COUT) + j * 2;
#pragma unroll
    for (int i = 0; i < CIN; ++i) {
        float2 w = *(const float2*)(wq + i * COUT);
#pragma unroll
        for (int b = 0; b < NB; ++b) {
            acc[b].x = fmaf(xs[b][i], w.x, acc[b].x);
            acc[b].y = fmaf(xs[b][i], w.y, acc[b].y);
        }
    }
    const unsigned base = swzu(2u * (unsigned)r + (unsigned)(j >> 2)) * 4u + (unsigned)(j & 3);
#pragma unroll
    for (int b = 0; b < NB; ++b)
        prLDS[b * PLANE + base] = pack_bf16(acc[b].x, acc[b].y);
}

__global__ __launch_bounds__(T) void caps_routing(const float* __restrict__ x,
                                                  const float* __restrict__ W,
                                                  float* __restrict__ out) {
    __shared__ unsigned prLDS[NB * PLANE];          // 147456 B: priors bf16x2, swizzled
    __shared__ float sred[NWAVE][20];               // [wave][comp 0..15, 16=sumExp]
    __shared__ __align__(16) float VLDS[NB][COUT];  // cumulative output (= logit state)

    const int tid  = threadIdx.x;
    const int lane = tid & 63;
    const int wv   = tid >> 6;

    // XCD-aware swizzle: contiguous widx per XCD -> <=2 capsules -> W L2-resident
    int g    = blockIdx.x;
    int widx = (g & 7) * (NBLK / 8) + (g >> 3);   // bijective, 640 % 8 == 0
    int c    = widx >> 6;                          // / (BATCH/NB = 64)
    int b0   = (widx & 63) * NB;

    const float* Wc = W + (size_t)c * (NROUTE * CIN * COUT);
    const float* xb = x + (size_t)b0 * XPLANE;

    // ---------------- Phase A: 9216 units = exactly 9 passes ----------------
#pragma unroll 1
    for (int pass = 0; pass < (NROUTE * 8) / T; ++pass) {
        phaseA_unit(pass * T + tid, Wc, xb, prLDS);
    }
    __syncthreads();

    // ---------------- Phase B: 4-way b-split, 3 routing iterations ----------
    // Waves 4b..4b+3 own batch element b (256 threads/b): 4 main routes +
    // half-row leftover per thread. All 16 waves busy; 3 butterflies/thread.
    const int bb   = wv >> 2;                 // batch element 0..3
    const int t256 = ((wv & 3) << 6) | lane;  // 0..255 within b-group
    const int h    = t256 & 1;                // leftover half
    const int r2   = 1024 + (t256 >> 1);      // leftover route
    const unsigned pbase = (unsigned)bb * PLANE;
    const int comp = ((lane & 1) << 3) | ((lane & 2) << 1) | ((lane & 4) >> 1) | ((lane & 8) >> 3);

#pragma unroll 1
    for (int it = 0; it < 3; ++it) {
        float s16[COUT];
        float se = 0.f;
#pragma unroll
        for (int o = 0; o < COUT; ++o) s16[o] = 0.f;

        // 4 main routes (independent bodies -> ILP)
#pragma unroll
        for (int q = 0; q < 4; ++q) {
            const int r = (q << 8) + t256;
            const unsigned d0 = pbase + swzu(2u * (unsigned)r) * 4u;
            const unsigned d1 = pbase + swzu(2u * (unsigned)r + 1u) * 4u;
            U4 qa, qb;
            qa.v = *(const uint4*)&prLDS[d0];
            qb.v = *(const uint4*)&prLDS[d1];
            float p[COUT];
#pragma unroll
            for (int u = 0; u < 4; ++u) {
                p[2 * u]     = blo(qa.u[u]);  p[2 * u + 1] = bhi(qa.u[u]);
                p[8 + 2 * u] = blo(qb.u[u]);  p[9 + 2 * u] = bhi(qb.u[u]);
            }
            float e;
            if (it > 0) {
                float d = 0.f;
#pragma unroll
                for (int u = 0; u < 4; ++u) {
                    float4 v4 = *(const float4*)&VLDS[bb][4 * u];   // broadcast read
                    d = fmaf(p[4 * u + 0], v4.x, d);
                    d = fmaf(p[4 * u + 1], v4.y, d);
                    d = fmaf(p[4 * u + 2], v4.z, d);
                    d = fmaf(p[4 * u + 3], v4.w, d);
                }
                e = __expf(d);   // logit = p . V (linearity), bounded ~|45|
            } else {
                e = 1.f;
            }
            se += e;
#pragma unroll
            for (int o = 0; o < COUT; ++o) s16[o] = fmaf(e, p[o], s16[o]);
        }

        // leftover route: half-row (8 outs), pair partner = lane^1 (same wave)
        {
            const unsigned dw = pbase + swzu(2u * (unsigned)r2 + (unsigned)h) * 4u;
            U4 q;
            q.v = *(const uint4*)&prLDS[dw];
            float pl[8];
#pragma unroll
            for (int u = 0; u < 4; ++u) { pl[2 * u] = blo(q.u[u]); pl[2 * u + 1] = bhi(q.u[u]); }
            float e2;
            if (it > 0) {
                float d2 = 0.f;
#pragma unroll
                for (int j = 0; j < 8; ++j) d2 = fmaf(pl[j], VLDS[bb][h * 8 + j], d2);
                d2 += __shfl_xor(d2, 1);    // combine halves
                e2 = __expf(d2);
            } else {
                e2 = 1.f;
            }
            se += 0.5f * e2;                // 2 lanes each add half of exp -> exact
#pragma unroll
            for (int j = 0; j < 8; ++j) {
                const float add = e2 * pl[j];
                s16[j]     += (h == 0) ? add : 0.f;
                s16[8 + j] += (h == 1) ? add : 0.f;
            }
        }

        const float sv  = wave_sum16(s16, lane);
        const float sev = wave_sum(se);
        if (lane < 16) sred[wv][comp] = sv;
        if (lane == 0) sred[wv][16]   = sev;
        __syncthreads();

        if (tid < NB * COUT) {          // 64 threads (1 wave): reduce 4 waves/b + squash
            const int b = tid >> 4, o = tid & 15;
            float S = 0.f, SE = 0.f;
#pragma unroll
            for (int k = 0; k < 4; ++k) {
                S  += sred[b * 4 + k][o];
                SE += sred[b * 4 + k][16];
            }
            const float tt = S / SE;
            float pq = tt * tt;
            pq += __shfl_xor(pq, 1); pq += __shfl_xor(pq, 2);
            pq += __shfl_xor(pq, 4); pq += __shfl_xor(pq, 8);   // |s|^2 per 16-group
            const float scale = pq / ((1.f + pq) * sqrtf(pq));
            const float val = tt * scale;
            if (it == 2) {
                out[((size_t)c * BATCH + b0 + b) * COUT + o] = val;
            } else {
                VLDS[b][o] = (it == 0) ? val : (VLDS[b][o] + val);  // cumulative V
            }
        }
        __syncthreads();
    }
}

extern "C" void kernel_launch(void* const* d_in, const int* in_sizes, int n_in,
                              void* d_out, int out_size, void* d_ws, size_t ws_size,
                              hipStream_t stream) {
    const float* x = (const float*)d_in[0];
    const float* w = (const float*)d_in[1];
    float* out = (float*)d_out;
    hipLaunchKernelGGL(caps_routing, dim3(NBLK), dim3(T), 0, stream, x, w, out);
}